// Round 1
// baseline (90.424 us; speedup 1.0000x reference)
//
#include <hip/hip_runtime.h>

// NLM smoothing: x[B=8, H=256, W=256, C=8] fp32, K=5, sigma=1, h=1, reflect pad.
// One thread per pixel. Channels (8 fp32 = 32B) loaded as two float4.
// Weight fusion: gk normalization cancels in w/sum(w); spatial and intensity
// Gaussians fuse into a single __expf per neighbor.

#define BATCH 8
#define NX 256
#define NY 256
#define CH 8
#define PAD 2

__device__ __forceinline__ int reflect_idx(int v) {
    // valid for v in [-2, 257] with N=256
    if (v < 0) v = -v;
    if (v > NY - 1) v = 2 * (NY - 1) - v;
    return v;
}

__global__ __launch_bounds__(256) void nlm_kernel(const float* __restrict__ x,
                                                  float* __restrict__ out) {
    const int idx = blockIdx.x * blockDim.x + threadIdx.x;  // pixel id, 0..524287
    const int j = idx & (NY - 1);
    const int i = (idx >> 8) & (NX - 1);
    const int b = idx >> 16;

    const float4* xv = (const float4*)x;
    // center pixel: two float4 at vector index idx*2
    const float4 c0 = xv[idx * 2 + 0];
    const float4 c1 = xv[idx * 2 + 1];

    float4 acc0 = make_float4(0.f, 0.f, 0.f, 0.f);
    float4 acc1 = make_float4(0.f, 0.f, 0.f, 0.f);
    float wsum = 0.f;

    const int bbase = b * (NX * NY);  // pixel index base for this batch

#pragma unroll
    for (int dr = -PAD; dr <= PAD; ++dr) {
        const int ii = reflect_idx(i + dr);
        const int rowbase = bbase + ii * NY;
#pragma unroll
        for (int dc = -PAD; dc <= PAD; ++dc) {
            const int jj = reflect_idx(j + dc);
            const int pidx = rowbase + jj;
            const float4 p0 = xv[pidx * 2 + 0];
            const float4 p1 = xv[pidx * 2 + 1];

            float d;
            float t;
            t = c0.x - p0.x; d  = t * t;
            t = c0.y - p0.y; d += t * t;
            t = c0.z - p0.z; d += t * t;
            t = c0.w - p0.w; d += t * t;
            t = c1.x - p1.x; d += t * t;
            t = c1.y - p1.y; d += t * t;
            t = c1.z - p1.z; d += t * t;
            t = c1.w - p1.w; d += t * t;

            // spatial gaussian exponent (sigma=1): 0.5*(dr^2+dc^2); h=1 for diff
            const float w = __expf(-(d + 0.5f * (float)(dr * dr + dc * dc)));

            acc0.x += w * p0.x; acc0.y += w * p0.y;
            acc0.z += w * p0.z; acc0.w += w * p0.w;
            acc1.x += w * p1.x; acc1.y += w * p1.y;
            acc1.z += w * p1.z; acc1.w += w * p1.w;
            wsum += w;
        }
    }

    const float inv = 1.0f / wsum;
    float4 o0, o1;
    o0.x = acc0.x * inv; o0.y = acc0.y * inv;
    o0.z = acc0.z * inv; o0.w = acc0.w * inv;
    o1.x = acc1.x * inv; o1.y = acc1.y * inv;
    o1.z = acc1.z * inv; o1.w = acc1.w * inv;

    float4* ov = (float4*)out;
    ov[idx * 2 + 0] = o0;
    ov[idx * 2 + 1] = o1;
}

extern "C" void kernel_launch(void* const* d_in, const int* in_sizes, int n_in,
                              void* d_out, int out_size, void* d_ws, size_t ws_size,
                              hipStream_t stream) {
    const float* x = (const float*)d_in[0];
    float* out = (float*)d_out;
    const int npix = BATCH * NX * NY;  // 524288
    nlm_kernel<<<npix / 256, 256, 0, stream>>>(x, out);
}

// Round 2
// 76.818 us; speedup vs baseline: 1.1771x; 1.1771x over previous
//
#include <hip/hip_runtime.h>

// NLM smoothing: x[B=8, H=256, W=256, C=8] fp32, K=5, sigma=1, h=1, reflect pad.
// LDS-tiled: block computes a 32(j) x 8(i) pixel tile; stages (8+4)x(32+4)=432
// pixels (two float4 each, 13824 B) into LDS, then each thread reads its 25
// neighbors via ds_read_b128 with compile-time immediate offsets.
// Weight fusion: gk normalization cancels in w/sum(w); spatial + intensity
// Gaussians fuse into one __expf per neighbor.

#define BATCH 8
#define NX 256
#define NY 256
#define HALO 2
#define TSJ 32
#define TSI 8
#define LW (TSJ + 2 * HALO)   // 36
#define LH (TSI + 2 * HALO)   // 12
#define NPIX (LW * LH)        // 432

__device__ __forceinline__ int reflect_idx(int v) {
    // valid for v in [-2, 257] with N=256
    if (v < 0) v = -v;
    if (v > NY - 1) v = 2 * (NY - 1) - v;
    return v;
}

__global__ __launch_bounds__(256) void nlm_kernel(const float4* __restrict__ xv,
                                                  float4* __restrict__ ov) {
    __shared__ float4 tile[NPIX * 2];

    const int t = threadIdx.x;
    const int bj0 = blockIdx.x * TSJ;
    const int bi0 = blockIdx.y * TSI;
    const int b = blockIdx.z;
    const int bbase = b * (NX * NY);

    // ---- stage tile (with reflect halo) into LDS ----
#pragma unroll
    for (int s0 = 0; s0 < NPIX * 2; s0 += 256) {
        const int s = s0 + t;
        if (s < NPIX * 2) {
            const int p = s >> 1;
            const int half = s & 1;
            const int lr = p / LW;
            const int lc = p - lr * LW;
            const int gi = reflect_idx(bi0 + lr - HALO);
            const int gj = reflect_idx(bj0 + lc - HALO);
            tile[s] = xv[(bbase + gi * NY + gj) * 2 + half];
        }
    }
    __syncthreads();

    // ---- per-thread pixel ----
    const int lj = t & (TSJ - 1);
    const int li = t >> 5;
    const int cpix = (li + HALO) * LW + (lj + HALO);

    const float4 c0 = tile[cpix * 2 + 0];
    const float4 c1 = tile[cpix * 2 + 1];

    float4 acc0 = make_float4(0.f, 0.f, 0.f, 0.f);
    float4 acc1 = make_float4(0.f, 0.f, 0.f, 0.f);
    float wsum = 0.f;

#pragma unroll
    for (int dr = -HALO; dr <= HALO; ++dr) {
#pragma unroll
        for (int dc = -HALO; dc <= HALO; ++dc) {
            const int pix = cpix + dr * LW + dc;   // constant offset from cpix
            const float4 p0 = tile[pix * 2 + 0];
            const float4 p1 = tile[pix * 2 + 1];

            float d, tt;
            tt = c0.x - p0.x; d  = tt * tt;
            tt = c0.y - p0.y; d += tt * tt;
            tt = c0.z - p0.z; d += tt * tt;
            tt = c0.w - p0.w; d += tt * tt;
            tt = c1.x - p1.x; d += tt * tt;
            tt = c1.y - p1.y; d += tt * tt;
            tt = c1.z - p1.z; d += tt * tt;
            tt = c1.w - p1.w; d += tt * tt;

            const float w = __expf(-(d + 0.5f * (float)(dr * dr + dc * dc)));

            acc0.x += w * p0.x; acc0.y += w * p0.y;
            acc0.z += w * p0.z; acc0.w += w * p0.w;
            acc1.x += w * p1.x; acc1.y += w * p1.y;
            acc1.z += w * p1.z; acc1.w += w * p1.w;
            wsum += w;
        }
    }

    const float inv = 1.0f / wsum;
    float4 o0, o1;
    o0.x = acc0.x * inv; o0.y = acc0.y * inv;
    o0.z = acc0.z * inv; o0.w = acc0.w * inv;
    o1.x = acc1.x * inv; o1.y = acc1.y * inv;
    o1.z = acc1.z * inv; o1.w = acc1.w * inv;

    const int oidx = bbase + (bi0 + li) * NY + (bj0 + lj);
    ov[oidx * 2 + 0] = o0;
    ov[oidx * 2 + 1] = o1;
}

extern "C" void kernel_launch(void* const* d_in, const int* in_sizes, int n_in,
                              void* d_out, int out_size, void* d_ws, size_t ws_size,
                              hipStream_t stream) {
    const float4* x = (const float4*)d_in[0];
    float4* out = (float4*)d_out;
    dim3 grid(NY / TSJ, NX / TSI, BATCH);  // 8 x 32 x 8 = 2048 blocks
    nlm_kernel<<<grid, 256, 0, stream>>>(x, out);
}